// Round 6
// baseline (266.654 us; speedup 1.0000x reference)
//
#include <hip/hip_runtime.h>
#include <hip/hip_bf16.h>
#include <hip/hip_fp16.h>
#include <stdint.h>

typedef __bf16 bf16_t;
typedef bf16_t bf16x8 __attribute__((ext_vector_type(8)));
typedef bf16_t bf16x4 __attribute__((ext_vector_type(4)));
typedef _Float16 f16x8 __attribute__((ext_vector_type(8)));
typedef float f32x4 __attribute__((ext_vector_type(4)));

#define BM 128
#define BN 256
#define BK 32

// async global->LDS, 16B per lane. LDS dst is wave-uniform base + lane*16;
// the GLOBAL source may be arbitrary per-lane (used for the bank swizzle).
__device__ __forceinline__ void gload_lds16(const void* g, void* l) {
    __builtin_amdgcn_global_load_lds(
        (const __attribute__((address_space(1))) void*)(uintptr_t)g,
        (__attribute__((address_space(3))) void*)(uintptr_t)l,
        16, 0, 0);
}

// ---------------------------------------------------------------------------
// NT-GEMM body, 128x256 tile, 4 waves (2x2), 4x8 MFMA 16x16x32 per wave.
// C[m,n] = scale * sum_k A[m,k]*B[n,k].
// LDS bank swizzle: 16B chunk slot jslot=(j+(row>>1))&3 -> 4-way conflict
// becomes 2-way (free, m136). Staging source offset compensates.
// EPI: 0 = bf16 row-major, 1 = f16 row-major, 2 = f32 row-major,
//      4 = bf16 transposed into Vt[b][d][s] (d=col-2048, b=row>>11, s=row&2047)
// ---------------------------------------------------------------------------
template <int EPI>
__device__ __forceinline__ void gemm_body(
    const bf16_t* __restrict__ A, long lda,
    const bf16_t* __restrict__ B, long ldb,
    void* __restrict__ Cv, long ldc,
    int k0beg, int k1end, float scale, int m0, int n0)
{
    __shared__ __align__(16) bf16_t As[BM * BK];   //  8 KB
    __shared__ __align__(16) bf16_t Bs[BN * BK];   // 16 KB

    const int tid = threadIdx.x;
    const int wid = tid >> 6, lane = tid & 63;
    const int wr = wid >> 1, wc = wid & 1;
    const int hw = lane >> 4, ln = lane & 15;

    // A staging: 512 chunks of 16B, 2 per thread.
    const bf16_t* srcA[2];
#pragma unroll
    for (int i = 0; i < 2; i++) {
        const int c = tid + i * 256;
        const int row = c >> 2;
        const int j = ((c & 3) - (row >> 1)) & 3;      // global k-chunk in this slot
        srcA[i] = A + (size_t)(m0 + row) * lda + j * 8;
    }
    // B staging: 1024 chunks of 16B, 4 per thread.
    const bf16_t* srcB[4];
#pragma unroll
    for (int q = 0; q < 4; q++) {
        const int c = tid + q * 256;
        const int row = c >> 2;
        const int j = ((c & 3) - (row >> 1)) & 3;
        srcB[q] = B + (size_t)(n0 + row) * ldb + j * 8;
    }

    f32x4 acc[4][8] = {};

    for (int k0 = k0beg; k0 < k1end; k0 += BK) {
        gload_lds16(srcA[0] + k0, &As[wid * 512]);
        gload_lds16(srcA[1] + k0, &As[2048 + wid * 512]);
#pragma unroll
        for (int q = 0; q < 4; q++)
            gload_lds16(srcB[q] + k0, &Bs[q * 2048 + wid * 512]);
        __syncthreads();

        bf16x8 af[4], bfr[8];
#pragma unroll
        for (int t = 0; t < 4; t++) {
            const int r = wr * 64 + t * 16 + ln;
            af[t] = *(const bf16x8*)&As[r * BK + (((hw + (r >> 1)) & 3) * 8)];
        }
#pragma unroll
        for (int u = 0; u < 8; u++) {
            const int rb = wc * 128 + u * 16 + ln;
            bfr[u] = *(const bf16x8*)&Bs[rb * BK + (((hw + (rb >> 1)) & 3) * 8)];
        }
#pragma unroll
        for (int ti = 0; ti < 4; ti++)
#pragma unroll
            for (int tj = 0; tj < 8; tj++)
                acc[ti][tj] = __builtin_amdgcn_mfma_f32_16x16x32_bf16(
                    af[ti], bfr[tj], acc[ti][tj], 0, 0, 0);
        __syncthreads();
    }

    // epilogue: C/D layout col=lane&15, row=(lane>>4)*4+reg (m89-verified)
#pragma unroll
    for (int ti = 0; ti < 4; ti++) {
        const int rbase = m0 + wr * 64 + ti * 16 + hw * 4;
#pragma unroll
        for (int tj = 0; tj < 8; tj++) {
            const int col = n0 + wc * 128 + tj * 16 + ln;
            if (EPI == 4) {
                // transposed bf16: 4 consecutive rows -> 8B contiguous in Vt
                const int bb = rbase >> 11;
                const int s  = rbase & 2047;
                const int d  = col - 2048;
                bf16x4 o;
#pragma unroll
                for (int rg = 0; rg < 4; rg++) o[rg] = (bf16_t)acc[ti][tj][rg];
                *(bf16x4*)&((bf16_t*)Cv)[(size_t)bb * 2097152 + (size_t)d * 2048 + s] = o;
            } else {
#pragma unroll
                for (int rg = 0; rg < 4; rg++) {
                    const float v = acc[ti][tj][rg] * scale;
                    const size_t idx = (size_t)(rbase + rg) * ldc + col;
                    if (EPI == 0)      ((bf16_t*)Cv)[idx]   = (bf16_t)v;
                    else if (EPI == 1) ((_Float16*)Cv)[idx] = (_Float16)v;
                    else               ((float*)Cv)[idx]    = v;
                }
            }
        }
    }
}

// ---------------------------------------------------------------------------
// GEMM1: [K|Q] = x*W^T row-major into QKVb (8192x2048); V written transposed
// into Vt[b][d][s]. M=8192, N=3072 (12 nblk of 256), K=1024. grid 768.
// XCD-pinned swizzle: xcd=lin&7 owns mblk [8x,8x+8); 3 n-phases of 4 nblks.
// Per-phase footprint A 2MB + B 2MB = one XCD L2.
// ---------------------------------------------------------------------------
__global__ __launch_bounds__(256, 2) void gemm1_qkv(
    const bf16_t* __restrict__ xb, const bf16_t* __restrict__ Wb,
    bf16_t* __restrict__ QKVb, bf16_t* __restrict__ Vt)
{
    const int lin = blockIdx.x;            // 0..767
    const int xcd = lin & 7;
    const int j   = lin >> 3;              // 0..95
    const int p   = j >> 5;                // 0..2
    const int w   = j & 31;                // 0..31
    const int mblk = xcd * 8 + (w >> 2);   // 0..63
    const int nblk = p * 4 + (w & 3);      // 0..11
    const int m0 = mblk * BM, n0 = nblk * BN;
    if (nblk < 8)
        gemm_body<0>(xb, 1024, Wb, 1024, QKVb, 2048, 0, 1024, 1.0f, m0, n0);
    else
        gemm_body<4>(xb, 1024, Wb, 1024, Vt, 2048, 0, 1024, 1.0f, m0, n0);
}

// ---------------------------------------------------------------------------
// GEMM2: S = scale * Q K^T per batch -> f16 logits. 128x256 blocks, causal:
// (my, nx2) active iff nx2 <= my/2. 72/batch * 4 = 288 blocks, heavy-first.
// ---------------------------------------------------------------------------
__global__ __launch_bounds__(256, 2) void qk_gemm(
    const bf16_t* __restrict__ QKVb, _Float16* __restrict__ S)
{
    const int b = blockIdx.x & 3;
    int rem = blockIdx.x >> 2;             // 0..71
    int my = 15, nx2 = 0;
#pragma unroll
    for (int m = 15; m >= 0; --m) {        // heavy strips first
        const int c = (m >> 1) + 1;
        if (rem < c) { my = m; nx2 = rem; break; }
        rem -= c;
    }
    const bf16_t* base = QKVb + (size_t)b * (2048L * 2048);
    gemm_body<1>(base + 1024, 2048,        // Q
                 base, 2048,               // K
                 S + (size_t)b * (2048L * 2048), 2048,
                 0, 1024, 0.03125f, my * BM, nx2 * BN);
}

// ---------------------------------------------------------------------------
// GEMM3: out = P * Vt^T per batch -> f32. 128x256 blocks, N=1024 (4 nx2),
// tri-K (Keff=m0+128). 16*4*4 = 256 blocks = exactly one round, heavy-first.
// ---------------------------------------------------------------------------
__global__ __launch_bounds__(256, 2) void gemm3_pv(
    const bf16_t* __restrict__ P, const bf16_t* __restrict__ Vt,
    float* __restrict__ out)
{
    const int b = blockIdx.x & 3;
    const int g = blockIdx.x >> 2;         // 0..63
    const int strip = 15 - (g >> 2);       // heavy first
    const int nx2 = g & 3;
    const int m0 = strip * BM;
    gemm_body<2>(P + (size_t)b * (2048L * 2048), 2048,
                 Vt + (size_t)b * (1024L * 2048), 2048,
                 out + (size_t)b * (2048L * 1024), 1024,
                 0, m0 + BM, 1.0f, m0, nx2 * BN);
}

// ---------------------------------------------------------------------------
// Merged input casts: blocks [0,8192) cast x (8M f32), [8192,11264) cast W (3M).
__global__ __launch_bounds__(256) void cast_all(
    const float* __restrict__ x,
    const float* __restrict__ Wk, const float* __restrict__ Wq,
    const float* __restrict__ Wv,
    bf16_t* __restrict__ xb, bf16_t* __restrict__ Wb)
{
    const int blk = blockIdx.x;
    const float* src;
    bf16_t* dst;
    if (blk < 8192) {
        const size_t i = ((size_t)blk * 256 + threadIdx.x) * 4;
        src = x + i;
        dst = xb + i;
    } else {
        const size_t j = ((size_t)(blk - 8192) * 256 + threadIdx.x) * 4;
        dst = Wb + j;
        if (j < (size_t)1048576)      src = Wk + j;
        else if (j < (size_t)2097152) src = Wq + (j - 1048576);
        else                          src = Wv + (j - 2097152);
    }
    const float4 v = *(const float4*)src;
    bf16x4 o;
    o.x = (bf16_t)v.x; o.y = (bf16_t)v.y; o.z = (bf16_t)v.z; o.w = (bf16_t)v.w;
    *(bf16x4*)dst = o;
}

__device__ __forceinline__ float wred_max(float v) {
#pragma unroll
    for (int o = 32; o; o >>= 1) v = fmaxf(v, __shfl_xor(v, o, 64));
    return v;
}
__device__ __forceinline__ float wred_sum(float v) {
#pragma unroll
    for (int o = 32; o; o >>= 1) v += __shfl_xor(v, o, 64);
    return v;
}

// one block per row; vectorized 16B loads/stores. f16 logits -> bf16 probs
// in place (cols > i masked to -inf -> 0 prob; unwritten poison cols masked too).
__global__ __launch_bounds__(256) void softmax_rows(_Float16* __restrict__ S)
{
    __shared__ float red[8];
    const int r = blockIdx.x;
    const int i = r & 2047;
    const int n = i + 1;
    _Float16* row = S + (size_t)r * 2048;
    const int tid = threadIdx.x;
    const int wid = tid >> 6, lane = tid & 63;
    const int base = tid * 8;

    const f16x8 v8 = *(const f16x8*)(row + base);
    float vals[8];
    float mx = -3e30f;
#pragma unroll
    for (int k = 0; k < 8; k++) {
        const float v = (base + k < n) ? (float)v8[k] : -3e30f;
        vals[k] = v;
        mx = fmaxf(mx, v);
    }
    mx = wred_max(mx);
    if (lane == 0) red[wid] = mx;
    __syncthreads();
    mx = fmaxf(fmaxf(red[0], red[1]), fmaxf(red[2], red[3]));

    float s = 0.f;
#pragma unroll
    for (int k = 0; k < 8; k++) {
        const float e = __expf(vals[k] - mx);
        vals[k] = e;
        s += e;
    }
    s = wred_sum(s);
    if (lane == 0) red[4 + wid] = s;
    __syncthreads();
    s = red[4] + red[5] + red[6] + red[7];
    const float inv = 1.0f / s;

    bf16x8 o;
#pragma unroll
    for (int k = 0; k < 8; k++) o[k] = (bf16_t)(vals[k] * inv);
    *(bf16x8*)((bf16_t*)row + base) = o;
}

// ---------------------------------------------------------------------------
extern "C" void kernel_launch(void* const* d_in, const int* in_sizes, int n_in,
                              void* d_out, int out_size, void* d_ws, size_t ws_size,
                              hipStream_t stream)
{
    const float* x  = (const float*)d_in[0];
    const float* Wk = (const float*)d_in[1];
    const float* Wq = (const float*)d_in[2];
    const float* Wv = (const float*)d_in[3];
    char* ws = (char*)d_ws;

    // ws layout (80 MB used):
    //   [0,32)   QKVb bf16 8192x2048  ([K|Q] columns only; V goes to Vt)
    //   [32,48)  Vt   bf16 4 x 1024x2048 (written transposed by GEMM1)
    //   [48,64)  xb   bf16 8192x1024   (dead after GEMM1)
    //   [64,70)  Wb   bf16 3072x1024   (dead after GEMM1)
    //   [48,80)  S    f16  4 x 2048x2048 logits (aliases xb+Wb, both dead)
    //            -> overwritten in place by bf16 P after softmax
    bf16_t*   QKVb = (bf16_t*)(ws);
    bf16_t*   Vt   = (bf16_t*)(ws + ((size_t)32 << 20));
    bf16_t*   xb   = (bf16_t*)(ws + ((size_t)48 << 20));
    bf16_t*   Wb   = (bf16_t*)(ws + ((size_t)64 << 20));
    _Float16* S    = (_Float16*)(ws + ((size_t)48 << 20));
    float*    out  = (float*)d_out;

    // 1. cast inputs to bf16
    cast_all<<<11264, 256, 0, stream>>>(x, Wk, Wq, Wv, xb, Wb);

    // 2. GEMM1 (XCD-pinned swizzle; V stored transposed -> no transpose kernel)
    gemm1_qkv<<<768, 256, 0, stream>>>(xb, Wb, QKVb, Vt);

    // 3. GEMM2: causal QK^T -> f16 logits, heavy-first, 288 blocks
    qk_gemm<<<288, 256, 0, stream>>>(QKVb, S);

    // 4. softmax rows (f16 logits -> bf16 probs in place)
    softmax_rows<<<8192, 256, 0, stream>>>(S);

    // 5. GEMM3: tri-K, single round (256 blocks), heavy-first
    gemm3_pv<<<256, 256, 0, stream>>>((bf16_t*)S, Vt, out);
}

// Round 7
// 238.342 us; speedup vs baseline: 1.1188x; 1.1188x over previous
//
#include <hip/hip_runtime.h>
#include <hip/hip_bf16.h>
#include <hip/hip_fp16.h>
#include <stdint.h>

typedef __bf16 bf16_t;
typedef bf16_t bf16x8 __attribute__((ext_vector_type(8)));
typedef bf16_t bf16x4 __attribute__((ext_vector_type(4)));
typedef _Float16 f16x8 __attribute__((ext_vector_type(8)));
typedef float f32x4 __attribute__((ext_vector_type(4)));

#define BM 128
#define BN 128
#define BK 32

// async global->LDS, 16B per lane. LDS dst is wave-uniform base + lane*16;
// the GLOBAL source may be arbitrary per-lane (used for the bank swizzle).
__device__ __forceinline__ void gload_lds16(const void* g, void* l) {
    __builtin_amdgcn_global_load_lds(
        (const __attribute__((address_space(1))) void*)(uintptr_t)g,
        (__attribute__((address_space(3))) void*)(uintptr_t)l,
        16, 0, 0);
}

// ---------------------------------------------------------------------------
// NT-GEMM body, 128x128 tile, 4 waves (2x2), 4x4 MFMA 16x16x32 per wave.
// C[m,n] = scale * sum_k A[m,k]*B[n,k].
// LDS bank swizzle (r6-verified, conflicts 6.3M->0): 16B slot within a row is
// rotated by (row>>1): slot s holds global k-chunk (s-(row>>1))&3. Staging
// compensates via per-lane source offset (global side of global_load_lds is
// scatter-capable; only the LDS side is lane-ordered).
// __shared__ buffers are hoisted to kernel scope (passed in) so multiple
// instantiations in one kernel share one 16 KB allocation (r6 bug: 48 KB).
// EPI: 0 = bf16 row-major, 1 = f16 row-major, 2 = f32 row-major,
//      4 = bf16 transposed into Vt[b][d][s] (d=col-2048, b=row>>11, s=row&2047)
// ---------------------------------------------------------------------------
template <int EPI>
__device__ __forceinline__ void gemm_body(
    bf16_t* __restrict__ As, bf16_t* __restrict__ Bs,
    const bf16_t* __restrict__ A, long lda,
    const bf16_t* __restrict__ B, long ldb,
    void* __restrict__ Cv, long ldc,
    int k0beg, int k1end, float scale, int m0, int n0)
{
    const int tid = threadIdx.x;
    const int wid = tid >> 6, lane = tid & 63;
    const int wr = wid >> 1, wc = wid & 1;
    const int hw = lane >> 4, ln = lane & 15;

    // staging: 512 chunks of 16B per matrix, 2 per thread; swizzled source.
    const bf16_t *srcA[2], *srcB[2];
#pragma unroll
    for (int i = 0; i < 2; i++) {
        const int c = tid + i * 256;
        const int row = c >> 2;
        const int j = ((c & 3) - (row >> 1)) & 3;   // global k-chunk for this slot
        srcA[i] = A + (size_t)(m0 + row) * lda + j * 8;
        srcB[i] = B + (size_t)(n0 + row) * ldb + j * 8;
    }

    f32x4 acc[4][4] = {};

    for (int k0 = k0beg; k0 < k1end; k0 += BK) {
        gload_lds16(srcA[0] + k0, &As[wid * 512]);
        gload_lds16(srcA[1] + k0, &As[2048 + wid * 512]);
        gload_lds16(srcB[0] + k0, &Bs[wid * 512]);
        gload_lds16(srcB[1] + k0, &Bs[2048 + wid * 512]);
        __syncthreads();

        bf16x8 af[4], bfr[4];
#pragma unroll
        for (int t = 0; t < 4; t++) {
            const int r  = wr * 64 + t * 16 + ln;
            const int rb = wc * 64 + t * 16 + ln;
            af[t]  = *(const bf16x8*)&As[r  * BK + (((hw + (r  >> 1)) & 3) * 8)];
            bfr[t] = *(const bf16x8*)&Bs[rb * BK + (((hw + (rb >> 1)) & 3) * 8)];
        }
#pragma unroll
        for (int ti = 0; ti < 4; ti++)
#pragma unroll
            for (int tj = 0; tj < 4; tj++)
                acc[ti][tj] = __builtin_amdgcn_mfma_f32_16x16x32_bf16(
                    af[ti], bfr[tj], acc[ti][tj], 0, 0, 0);
        __syncthreads();
    }

    // epilogue: C/D layout col=lane&15, row=(lane>>4)*4+reg (m89-verified)
#pragma unroll
    for (int ti = 0; ti < 4; ti++) {
        const int rbase = m0 + wr * 64 + ti * 16 + hw * 4;
#pragma unroll
        for (int tj = 0; tj < 4; tj++) {
            const int col = n0 + wc * 64 + tj * 16 + ln;
            if (EPI == 4) {
                // transposed bf16: 4 consecutive rows -> 8B contiguous in Vt
                const int bb = rbase >> 11;
                const int s  = rbase & 2047;
                const int d  = col - 2048;
                bf16x4 o;
#pragma unroll
                for (int rg = 0; rg < 4; rg++) o[rg] = (bf16_t)acc[ti][tj][rg];
                *(bf16x4*)&((bf16_t*)Cv)[(size_t)bb * 2097152 + (size_t)d * 2048 + s] = o;
            } else {
#pragma unroll
                for (int rg = 0; rg < 4; rg++) {
                    const float v = acc[ti][tj][rg] * scale;
                    const size_t idx = (size_t)(rbase + rg) * ldc + col;
                    if (EPI == 0)      ((bf16_t*)Cv)[idx]   = (bf16_t)v;
                    else if (EPI == 1) ((_Float16*)Cv)[idx] = (_Float16)v;
                    else               ((float*)Cv)[idx]    = v;
                }
            }
        }
    }
}

// ---------------------------------------------------------------------------
// GEMM1: [K|Q] = x*W^T row-major into QKVb (8192x2048); V written transposed
// into Vt[b][d][s]. M=8192, N=3072 (24 nblk of 128), K=1024. grid 1536.
// XCD-pinned swizzle (r5-verified: FETCH 138->49 MB): xcd=lin&7 owns mblk
// [8x,8x+8); 3 n-phases of 8 nblks; per-phase footprint 4 MB = one XCD L2.
// ---------------------------------------------------------------------------
__global__ __launch_bounds__(256) void gemm1_qkv(
    const bf16_t* __restrict__ xb, const bf16_t* __restrict__ Wb,
    bf16_t* __restrict__ QKVb, bf16_t* __restrict__ Vt)
{
    __shared__ __align__(16) bf16_t As[BM * BK];
    __shared__ __align__(16) bf16_t Bs[BN * BK];
    const int lin = blockIdx.x;            // 0..1535
    const int xcd = lin & 7;
    const int j   = lin >> 3;              // 0..191
    const int p   = j >> 6;                // 0..2
    const int w   = j & 63;                // 0..63
    const int mblk = xcd * 8 + (w >> 3);   // 0..63
    const int nblk = p * 8 + (w & 7);      // 0..23
    const int m0 = mblk * BM, n0 = nblk * BN;
    if (nblk < 16)
        gemm_body<0>(As, Bs, xb, 1024, Wb, 1024, QKVb, 2048, 0, 1024, 1.0f, m0, n0);
    else
        gemm_body<4>(As, Bs, xb, 1024, Wb, 1024, Vt, 2048, 0, 1024, 1.0f, m0, n0);
}

// ---------------------------------------------------------------------------
// GEMM2: S = scale * Q K^T per batch -> f16 logits. Causal: (my,nx) active iff
// nx <= my -> 136/batch, 544 blocks, heavy strips first, batch fastest.
// ---------------------------------------------------------------------------
__global__ __launch_bounds__(256) void qk_gemm(
    const bf16_t* __restrict__ QKVb, _Float16* __restrict__ S)
{
    __shared__ __align__(16) bf16_t As[BM * BK];
    __shared__ __align__(16) bf16_t Bs[BN * BK];
    const int b = blockIdx.x & 3;
    int rem = blockIdx.x >> 2;             // 0..135
    int my = 15, nx = 0;
#pragma unroll
    for (int m = 15; m >= 0; --m) {        // heavy strips first
        if (rem < m + 1) { my = m; nx = rem; break; }
        rem -= m + 1;
    }
    const bf16_t* base = QKVb + (size_t)b * (2048L * 2048);
    gemm_body<1>(As, Bs,
                 base + 1024, 2048,        // Q
                 base, 2048,               // K
                 S + (size_t)b * (2048L * 2048), 2048,
                 0, 1024, 0.03125f, my * BM, nx * BN);
}

// ---------------------------------------------------------------------------
// GEMM3: out = P * Vt^T per batch -> f32. tri-K (Keff=m0+128), grid 512,
// heavy strips first, batch fastest.
// ---------------------------------------------------------------------------
__global__ __launch_bounds__(256) void gemm3_pv(
    const bf16_t* __restrict__ P, const bf16_t* __restrict__ Vt,
    float* __restrict__ out)
{
    __shared__ __align__(16) bf16_t As[BM * BK];
    __shared__ __align__(16) bf16_t Bs[BN * BK];
    const int id = blockIdx.x;
    const int strip = 15 - (id >> 5);      // heavy first
    const int nx = (id >> 2) & 7;
    const int b = id & 3;
    const int m0 = strip * BM;
    gemm_body<2>(As, Bs,
                 P + (size_t)b * (2048L * 2048), 2048,
                 Vt + (size_t)b * (1024L * 2048), 2048,
                 out + (size_t)b * (2048L * 1024), 1024,
                 0, m0 + BM, 1.0f, m0, nx * BN);
}

// ---------------------------------------------------------------------------
// Merged input casts: blocks [0,8192) cast x (8M f32), [8192,11264) cast W (3M).
__global__ __launch_bounds__(256) void cast_all(
    const float* __restrict__ x,
    const float* __restrict__ Wk, const float* __restrict__ Wq,
    const float* __restrict__ Wv,
    bf16_t* __restrict__ xb, bf16_t* __restrict__ Wb)
{
    const int blk = blockIdx.x;
    const float* src;
    bf16_t* dst;
    if (blk < 8192) {
        const size_t i = ((size_t)blk * 256 + threadIdx.x) * 4;
        src = x + i;
        dst = xb + i;
    } else {
        const size_t j = ((size_t)(blk - 8192) * 256 + threadIdx.x) * 4;
        dst = Wb + j;
        if (j < (size_t)1048576)      src = Wk + j;
        else if (j < (size_t)2097152) src = Wq + (j - 1048576);
        else                          src = Wv + (j - 2097152);
    }
    const float4 v = *(const float4*)src;
    bf16x4 o;
    o.x = (bf16_t)v.x; o.y = (bf16_t)v.y; o.z = (bf16_t)v.z; o.w = (bf16_t)v.w;
    *(bf16x4*)dst = o;
}

__device__ __forceinline__ float wred_max(float v) {
#pragma unroll
    for (int o = 32; o; o >>= 1) v = fmaxf(v, __shfl_xor(v, o, 64));
    return v;
}
__device__ __forceinline__ float wred_sum(float v) {
#pragma unroll
    for (int o = 32; o; o >>= 1) v += __shfl_xor(v, o, 64);
    return v;
}

// one block per row; vectorized 16B loads/stores. f16 logits -> bf16 probs
// in place (cols > i masked to -inf -> 0 prob; unwritten poison cols masked too).
__global__ __launch_bounds__(256) void softmax_rows(_Float16* __restrict__ S)
{
    __shared__ float red[8];
    const int r = blockIdx.x;
    const int i = r & 2047;
    const int n = i + 1;
    _Float16* row = S + (size_t)r * 2048;
    const int tid = threadIdx.x;
    const int wid = tid >> 6, lane = tid & 63;
    const int base = tid * 8;

    const f16x8 v8 = *(const f16x8*)(row + base);
    float vals[8];
    float mx = -3e30f;
#pragma unroll
    for (int k = 0; k < 8; k++) {
        const float v = (base + k < n) ? (float)v8[k] : -3e30f;
        vals[k] = v;
        mx = fmaxf(mx, v);
    }
    mx = wred_max(mx);
    if (lane == 0) red[wid] = mx;
    __syncthreads();
    mx = fmaxf(fmaxf(red[0], red[1]), fmaxf(red[2], red[3]));

    float s = 0.f;
#pragma unroll
    for (int k = 0; k < 8; k++) {
        const float e = __expf(vals[k] - mx);
        vals[k] = e;
        s += e;
    }
    s = wred_sum(s);
    if (lane == 0) red[4 + wid] = s;
    __syncthreads();
    s = red[4] + red[5] + red[6] + red[7];
    const float inv = 1.0f / s;

    bf16x8 o;
#pragma unroll
    for (int k = 0; k < 8; k++) o[k] = (bf16_t)(vals[k] * inv);
    *(bf16x8*)((bf16_t*)row + base) = o;
}

// ---------------------------------------------------------------------------
extern "C" void kernel_launch(void* const* d_in, const int* in_sizes, int n_in,
                              void* d_out, int out_size, void* d_ws, size_t ws_size,
                              hipStream_t stream)
{
    const float* x  = (const float*)d_in[0];
    const float* Wk = (const float*)d_in[1];
    const float* Wq = (const float*)d_in[2];
    const float* Wv = (const float*)d_in[3];
    char* ws = (char*)d_ws;

    // ws layout (80 MB used):
    //   [0,32)   QKVb bf16 8192x2048  ([K|Q] columns only; V goes to Vt)
    //   [32,48)  Vt   bf16 4 x 1024x2048 (written transposed by GEMM1)
    //   [48,64)  xb   bf16 8192x1024   (dead after GEMM1)
    //   [64,70)  Wb   bf16 3072x1024   (dead after GEMM1)
    //   [48,80)  S    f16  4 x 2048x2048 logits (aliases xb+Wb, both dead)
    //            -> overwritten in place by bf16 P after softmax
    bf16_t*   QKVb = (bf16_t*)(ws);
    bf16_t*   Vt   = (bf16_t*)(ws + ((size_t)32 << 20));
    bf16_t*   xb   = (bf16_t*)(ws + ((size_t)48 << 20));
    bf16_t*   Wb   = (bf16_t*)(ws + ((size_t)64 << 20));
    _Float16* S    = (_Float16*)(ws + ((size_t)48 << 20));
    float*    out  = (float*)d_out;

    // 1. cast inputs to bf16
    cast_all<<<11264, 256, 0, stream>>>(x, Wk, Wq, Wv, xb, Wb);

    // 2. GEMM1 (XCD-pinned swizzle; V stored transposed -> no transpose kernel)
    gemm1_qkv<<<1536, 256, 0, stream>>>(xb, Wb, QKVb, Vt);

    // 3. GEMM2: causal QK^T -> f16 logits, heavy-first, 544 blocks
    qk_gemm<<<544, 256, 0, stream>>>(QKVb, S);

    // 4. softmax rows (f16 logits -> bf16 probs in place)
    softmax_rows<<<8192, 256, 0, stream>>>(S);

    // 5. GEMM3: tri-K, heavy-first, 512 blocks
    gemm3_pv<<<512, 256, 0, stream>>>((bf16_t*)S, Vt, out);
}

// Round 8
// 226.227 us; speedup vs baseline: 1.1787x; 1.0536x over previous
//
#include <hip/hip_runtime.h>
#include <hip/hip_bf16.h>
#include <hip/hip_fp16.h>
#include <stdint.h>

typedef __bf16 bf16_t;
typedef bf16_t bf16x8 __attribute__((ext_vector_type(8)));
typedef bf16_t bf16x4 __attribute__((ext_vector_type(4)));
typedef float f32x4 __attribute__((ext_vector_type(4)));

#define BM 128
#define BN 128
#define BK 32

// async global->LDS, 16B per lane. LDS dst is wave-uniform base + lane*16;
// the GLOBAL source may be arbitrary per-lane (used for the bank swizzle).
__device__ __forceinline__ void gload_lds16(const void* g, void* l) {
    __builtin_amdgcn_global_load_lds(
        (const __attribute__((address_space(1))) void*)(uintptr_t)g,
        (__attribute__((address_space(3))) void*)(uintptr_t)l,
        16, 0, 0);
}

// ---------------------------------------------------------------------------
// NT-GEMM body, 128x128 tile, 4 waves (2x2), 4x4 MFMA 16x16x32 per wave.
// C[m,n] = scale * sum_k A[m,k]*B[n,k].
// LDS bank swizzle (r6-verified, conflicts 6.3M->0): slot s of a row holds
// global k-chunk (s-(row>>1))&3; staging compensates on the global side.
// __shared__ passed in so multiple instantiations share one allocation (r6 bug).
// EPI: 0 = bf16 row-major store                        (gemm1 K|Q)
//      2 = f32 store, divided by rs[row]               (gemm3)
//      3 = exp(v) causal-masked bf16 store + atomic row-sum into rs  (qk)
//      4 = bf16 transposed into Vt[b][d][s]            (gemm1 V)
// ---------------------------------------------------------------------------
template <int EPI>
__device__ __forceinline__ void gemm_body(
    bf16_t* __restrict__ As, bf16_t* __restrict__ Bs,
    const bf16_t* __restrict__ A, long lda,
    const bf16_t* __restrict__ B, long ldb,
    void* __restrict__ Cv, long ldc,
    int k0beg, int k1end, float scale, int m0, int n0,
    float* __restrict__ rs)
{
    const int tid = threadIdx.x;
    const int wid = tid >> 6, lane = tid & 63;
    const int wr = wid >> 1, wc = wid & 1;
    const int hw = lane >> 4, ln = lane & 15;

    // staging: 512 chunks of 16B per matrix, 2 per thread; swizzled source.
    const bf16_t *srcA[2], *srcB[2];
#pragma unroll
    for (int i = 0; i < 2; i++) {
        const int c = tid + i * 256;
        const int row = c >> 2;
        const int j = ((c & 3) - (row >> 1)) & 3;   // global k-chunk for this slot
        srcA[i] = A + (size_t)(m0 + row) * lda + j * 8;
        srcB[i] = B + (size_t)(n0 + row) * ldb + j * 8;
    }

    f32x4 acc[4][4] = {};

    for (int k0 = k0beg; k0 < k1end; k0 += BK) {
        gload_lds16(srcA[0] + k0, &As[wid * 512]);
        gload_lds16(srcA[1] + k0, &As[2048 + wid * 512]);
        gload_lds16(srcB[0] + k0, &Bs[wid * 512]);
        gload_lds16(srcB[1] + k0, &Bs[2048 + wid * 512]);
        __syncthreads();

        bf16x8 af[4], bfr[4];
#pragma unroll
        for (int t = 0; t < 4; t++) {
            const int r  = wr * 64 + t * 16 + ln;
            const int rb = wc * 64 + t * 16 + ln;
            af[t]  = *(const bf16x8*)&As[r  * BK + (((hw + (r  >> 1)) & 3) * 8)];
            bfr[t] = *(const bf16x8*)&Bs[rb * BK + (((hw + (rb >> 1)) & 3) * 8)];
        }
#pragma unroll
        for (int ti = 0; ti < 4; ti++)
#pragma unroll
            for (int tj = 0; tj < 4; tj++)
                acc[ti][tj] = __builtin_amdgcn_mfma_f32_16x16x32_bf16(
                    af[ti], bfr[tj], acc[ti][tj], 0, 0, 0);
        __syncthreads();
    }

    // epilogue: C/D layout col=lane&15, row=(lane>>4)*4+reg (m89-verified)
#pragma unroll
    for (int ti = 0; ti < 4; ti++) {
        const int rbase = m0 + wr * 64 + ti * 16 + hw * 4;
        f32x4 inv4;
        if (EPI == 2) {
            const float4 r4 = *(const float4*)&rs[rbase];
            inv4[0] = 1.0f / r4.x; inv4[1] = 1.0f / r4.y;
            inv4[2] = 1.0f / r4.z; inv4[3] = 1.0f / r4.w;
        }
        float part[4] = {0.f, 0.f, 0.f, 0.f};   // EPI 3: per-row partial sums
#pragma unroll
        for (int tj = 0; tj < 4; tj++) {
            const int col = n0 + wc * 64 + tj * 16 + ln;
            if (EPI == 4) {
                // transposed bf16: 4 consecutive rows -> 8B contiguous in Vt
                const int bb = rbase >> 11;
                const int s  = rbase & 2047;
                const int d  = col - 2048;
                bf16x4 o;
#pragma unroll
                for (int rg = 0; rg < 4; rg++) o[rg] = (bf16_t)acc[ti][tj][rg];
                *(bf16x4*)&((bf16_t*)Cv)[(size_t)bb * 2097152 + (size_t)d * 2048 + s] = o;
            } else {
#pragma unroll
                for (int rg = 0; rg < 4; rg++) {
                    const size_t idx = (size_t)(rbase + rg) * ldc + col;
                    if (EPI == 0) {
                        ((bf16_t*)Cv)[idx] = (bf16_t)(acc[ti][tj][rg]);
                    } else if (EPI == 2) {
                        ((float*)Cv)[idx] = acc[ti][tj][rg] * inv4[rg];
                    } else {  // EPI 3: exp + causal mask + row-sum
                        const float e = (col <= rbase + rg)
                                      ? __expf(acc[ti][tj][rg] * scale) : 0.0f;
                        part[rg] += e;
                        ((bf16_t*)Cv)[idx] = (bf16_t)e;
                    }
                }
            }
        }
        if (EPI == 3) {
#pragma unroll
            for (int rg = 0; rg < 4; rg++) {
                float p = part[rg];
                p += __shfl_xor(p, 1, 64);
                p += __shfl_xor(p, 2, 64);
                p += __shfl_xor(p, 4, 64);
                p += __shfl_xor(p, 8, 64);
                if (ln == 0) atomicAdd(&rs[rbase + rg], p);
            }
        }
    }
}

// ---------------------------------------------------------------------------
// GEMM1: [K|Q] = x*W^T row-major into QKVb (8192x2048); V written transposed
// into Vt[b][d][s]. M=8192, N=3072 (24 nblk of 128), K=1024. grid 1536.
// XCD-pinned swizzle (r5-verified: FETCH 138->49 MB): xcd=lin&7 owns mblk
// [8x,8x+8); 3 n-phases of 8 nblks; per-phase footprint 4 MB = one XCD L2.
// ---------------------------------------------------------------------------
__global__ __launch_bounds__(256) void gemm1_qkv(
    const bf16_t* __restrict__ xb, const bf16_t* __restrict__ Wb,
    bf16_t* __restrict__ QKVb, bf16_t* __restrict__ Vt)
{
    __shared__ __align__(16) bf16_t As[BM * BK];
    __shared__ __align__(16) bf16_t Bs[BN * BK];
    const int lin = blockIdx.x;            // 0..1535
    const int xcd = lin & 7;
    const int j   = lin >> 3;              // 0..191
    const int p   = j >> 6;                // 0..2
    const int w   = j & 63;                // 0..63
    const int mblk = xcd * 8 + (w >> 3);   // 0..63
    const int nblk = p * 8 + (w & 7);      // 0..23
    const int m0 = mblk * BM, n0 = nblk * BN;
    if (nblk < 16)
        gemm_body<0>(As, Bs, xb, 1024, Wb, 1024, QKVb, 2048,
                     0, 1024, 1.0f, m0, n0, nullptr);
    else
        gemm_body<4>(As, Bs, xb, 1024, Wb, 1024, Vt, 2048,
                     0, 1024, 1.0f, m0, n0, nullptr);
}

// ---------------------------------------------------------------------------
// GEMM2+exp: E = exp(scale*Q K^T) per batch, causal-masked, bf16; row sums
// accumulated into rowsum (f32, pre-zeroed). 544 blocks, heavy-first.
// ---------------------------------------------------------------------------
__global__ __launch_bounds__(256) void qk_gemm(
    const bf16_t* __restrict__ QKVb, bf16_t* __restrict__ E,
    float* __restrict__ rowsum)
{
    __shared__ __align__(16) bf16_t As[BM * BK];
    __shared__ __align__(16) bf16_t Bs[BN * BK];
    const int b = blockIdx.x & 3;
    int rem = blockIdx.x >> 2;             // 0..135
    int my = 15, nx = 0;
#pragma unroll
    for (int m = 15; m >= 0; --m) {        // heavy strips first
        if (rem < m + 1) { my = m; nx = rem; break; }
        rem -= m + 1;
    }
    const bf16_t* base = QKVb + (size_t)b * (2048L * 2048);
    gemm_body<3>(As, Bs,
                 base + 1024, 2048,        // Q
                 base, 2048,               // K
                 E + (size_t)b * (2048L * 2048), 2048,
                 0, 1024, 0.03125f, my * BM, nx * BN,
                 rowsum + b * 2048);
}

// ---------------------------------------------------------------------------
// GEMM3: out = (E * Vt^T) / rowsum per batch -> f32. tri-K (Keff=m0+128),
// grid 512, heavy strips first, batch fastest.
// ---------------------------------------------------------------------------
__global__ __launch_bounds__(256) void gemm3_pv(
    const bf16_t* __restrict__ E, const bf16_t* __restrict__ Vt,
    const float* __restrict__ rowsum, float* __restrict__ out)
{
    __shared__ __align__(16) bf16_t As[BM * BK];
    __shared__ __align__(16) bf16_t Bs[BN * BK];
    const int id = blockIdx.x;
    const int strip = 15 - (id >> 5);      // heavy first
    const int nx = (id >> 2) & 7;
    const int b = id & 3;
    const int m0 = strip * BM;
    gemm_body<2>(As, Bs,
                 E + (size_t)b * (2048L * 2048), 2048,
                 Vt + (size_t)b * (1024L * 2048), 2048,
                 out + (size_t)b * (2048L * 1024), 1024,
                 0, m0 + BM, 1.0f, m0, nx * BN,
                 (float*)rowsum + b * 2048);
}

// ---------------------------------------------------------------------------
// Merged input casts: blocks [0,8192) cast x, [8192,11264) cast W,
// [11264,11272) zero the rowsum array (4x2048 f32).
__global__ __launch_bounds__(256) void cast_all(
    const float* __restrict__ x,
    const float* __restrict__ Wk, const float* __restrict__ Wq,
    const float* __restrict__ Wv,
    bf16_t* __restrict__ xb, bf16_t* __restrict__ Wb,
    float* __restrict__ rowsum)
{
    const int blk = blockIdx.x;
    if (blk >= 11264) {
        const size_t i = ((size_t)(blk - 11264) * 256 + threadIdx.x) * 4;
        *(float4*)(rowsum + i) = make_float4(0.f, 0.f, 0.f, 0.f);
        return;
    }
    const float* src;
    bf16_t* dst;
    if (blk < 8192) {
        const size_t i = ((size_t)blk * 256 + threadIdx.x) * 4;
        src = x + i;
        dst = xb + i;
    } else {
        const size_t j = ((size_t)(blk - 8192) * 256 + threadIdx.x) * 4;
        dst = Wb + j;
        if (j < (size_t)1048576)      src = Wk + j;
        else if (j < (size_t)2097152) src = Wq + (j - 1048576);
        else                          src = Wv + (j - 2097152);
    }
    const float4 v = *(const float4*)src;
    bf16x4 o;
    o.x = (bf16_t)v.x; o.y = (bf16_t)v.y; o.z = (bf16_t)v.z; o.w = (bf16_t)v.w;
    *(bf16x4*)dst = o;
}

// ---------------------------------------------------------------------------
extern "C" void kernel_launch(void* const* d_in, const int* in_sizes, int n_in,
                              void* d_out, int out_size, void* d_ws, size_t ws_size,
                              hipStream_t stream)
{
    const float* x  = (const float*)d_in[0];
    const float* Wk = (const float*)d_in[1];
    const float* Wq = (const float*)d_in[2];
    const float* Wv = (const float*)d_in[3];
    char* ws = (char*)d_ws;

    // ws layout (81 MB used):
    //   [0,32)   QKVb bf16 8192x2048  ([K|Q] columns only; V goes to Vt)
    //   [32,48)  Vt   bf16 4 x 1024x2048 (written transposed by GEMM1)
    //   [48,64)  xb   bf16 8192x1024   (dead after GEMM1)
    //   [64,70)  Wb   bf16 3072x1024   (dead after GEMM1)
    //   [48,80)  E    bf16 4 x 2048x2048 exp-logits (aliases xb+Wb, both dead)
    //   [80,81)  rowsum f32 4x2048 (zeroed by cast_all)
    bf16_t* QKVb   = (bf16_t*)(ws);
    bf16_t* Vt     = (bf16_t*)(ws + ((size_t)32 << 20));
    bf16_t* xb     = (bf16_t*)(ws + ((size_t)48 << 20));
    bf16_t* Wb     = (bf16_t*)(ws + ((size_t)64 << 20));
    bf16_t* E      = (bf16_t*)(ws + ((size_t)48 << 20));
    float*  rowsum = (float*)(ws + ((size_t)80 << 20));
    float*  out    = (float*)d_out;

    // 1. cast inputs to bf16 + zero rowsum
    cast_all<<<11272, 256, 0, stream>>>(x, Wk, Wq, Wv, xb, Wb, rowsum);

    // 2. GEMM1 (XCD-pinned swizzle; V stored transposed -> no transpose kernel)
    gemm1_qkv<<<1536, 256, 0, stream>>>(xb, Wb, QKVb, Vt);

    // 3. GEMM2: causal exp(QK^T) -> bf16 E + atomic row sums (no softmax kernel)
    qk_gemm<<<544, 256, 0, stream>>>(QKVb, E, rowsum);

    // 4. GEMM3: out = (E Vt^T)/rowsum, tri-K, heavy-first
    gemm3_pv<<<512, 256, 0, stream>>>(E, Vt, rowsum, out);
}